// Round 1
// baseline (123.864 us; speedup 1.0000x reference)
//
#include <hip/hip_runtime.h>

// ContrasPQ forward = per-(b,p) nearest-code lookup.
// out[b, p*8 .. p*8+7] = codebook[p, argmin_k ||v[b,p]-c[p,k]||^2, :]
// argmin computed via s_k = sum_d (-2*c_kd)*v_d + ||c_k||^2 (drops ||v||^2,
// constant in k). Strict-less update over ascending k == jnp.argmax first-index
// tie-break.

#define TPB 256   // threads per block
#define KBQ 4     // queries (b rows) per thread

namespace {
constexpr int kB   = 8192;
constexpr int kEMB = 768;
constexpr int kP   = 96;
constexpr int kK   = 256;
constexpr int kD   = 8;
}

__global__ __launch_bounds__(TPB, 3)
void pq_argmin_kernel(const float* __restrict__ vecs,
                      const float* __restrict__ codebook,
                      float* __restrict__ out)
{
    // codebook slice for this p, pre-scaled by -2, plus ||c||^2 (9 KB LDS)
    __shared__ alignas(16) float lds_code[kK][kD];
    __shared__ alignas(16) float lds_c2[kK];

    const int p = blockIdx.y;
    const int t = threadIdx.x;

    // ---- stage codebook[p] into LDS (coalesced: thread t loads code t) ----
    {
        const float4* cb4 =
            reinterpret_cast<const float4*>(codebook + (size_t)p * kK * kD);
        float4 a = cb4[2 * t];
        float4 b = cb4[2 * t + 1];
        float c2 = a.x * a.x + a.y * a.y + a.z * a.z + a.w * a.w +
                   b.x * b.x + b.y * b.y + b.z * b.z + b.w * b.w;
        float4* lc = reinterpret_cast<float4*>(&lds_code[t][0]);
        lc[0] = make_float4(-2.0f * a.x, -2.0f * a.y, -2.0f * a.z, -2.0f * a.w);
        lc[1] = make_float4(-2.0f * b.x, -2.0f * b.y, -2.0f * b.z, -2.0f * b.w);
        lds_c2[t] = c2;
    }
    __syncthreads();

    // ---- load KBQ query subvectors (8 floats each, 2x float4) ----
    const int b0 = blockIdx.x * (TPB * KBQ) + t;

    float v[KBQ][kD];
#pragma unroll
    for (int q = 0; q < KBQ; ++q) {
        const float4* vp = reinterpret_cast<const float4*>(
            vecs + (size_t)(b0 + q * TPB) * kEMB + p * kD);
        float4 x = vp[0];
        float4 y = vp[1];
        v[q][0] = x.x; v[q][1] = x.y; v[q][2] = x.z; v[q][3] = x.w;
        v[q][4] = y.x; v[q][5] = y.y; v[q][6] = y.z; v[q][7] = y.w;
    }

    float best[KBQ];
    int   bidx[KBQ];
#pragma unroll
    for (int q = 0; q < KBQ; ++q) {
        best[q] = __builtin_inff();
        bidx[q] = 0;
    }

    // ---- main loop: 256 codes, LDS broadcast reads, 4 queries/thread ----
#pragma unroll 4
    for (int k = 0; k < kK; ++k) {
        const float4 c0  = *reinterpret_cast<const float4*>(&lds_code[k][0]);
        const float4 c1  = *reinterpret_cast<const float4*>(&lds_code[k][4]);
        const float  c2k = lds_c2[k];
#pragma unroll
        for (int q = 0; q < KBQ; ++q) {
            float s = fmaf(c0.x, v[q][0], c2k);
            s = fmaf(c0.y, v[q][1], s);
            s = fmaf(c0.z, v[q][2], s);
            s = fmaf(c0.w, v[q][3], s);
            s = fmaf(c1.x, v[q][4], s);
            s = fmaf(c1.y, v[q][5], s);
            s = fmaf(c1.z, v[q][6], s);
            s = fmaf(c1.w, v[q][7], s);
            if (s < best[q]) {   // strict <: ties keep lower k (ref argmax)
                best[q] = s;
                bidx[q] = k;
            }
        }
    }

    // ---- epilogue: gather winning codebook rows (L2-hot) and store ----
#pragma unroll
    for (int q = 0; q < KBQ; ++q) {
        const float4* cr = reinterpret_cast<const float4*>(
            codebook + ((size_t)p * kK + bidx[q]) * kD);
        float4 r0 = cr[0];
        float4 r1 = cr[1];
        float4* op = reinterpret_cast<float4*>(
            out + (size_t)(b0 + q * TPB) * kEMB + p * kD);
        op[0] = r0;
        op[1] = r1;
    }
}

extern "C" void kernel_launch(void* const* d_in, const int* in_sizes, int n_in,
                              void* d_out, int out_size, void* d_ws, size_t ws_size,
                              hipStream_t stream)
{
    const float* vecs     = (const float*)d_in[0];
    const float* codebook = (const float*)d_in[1];
    float* out            = (float*)d_out;

    dim3 grid(kB / (TPB * KBQ), kP, 1);  // (8, 96)
    dim3 block(TPB, 1, 1);
    hipLaunchKernelGGL(pq_argmin_kernel, grid, block, 0, stream,
                       vecs, codebook, out);
}